// Round 3
// baseline (538.656 us; speedup 1.0000x reference)
//
#include <hip/hip_runtime.h>
#include <math.h>

#define B_  32
#define L_  4096
#define H_  512
#define V_  32000
#define MBLK 64

typedef __attribute__((ext_vector_type(4))) float f32x4;
typedef __attribute__((ext_vector_type(2))) float f32x2;
typedef __attribute__((ext_vector_type(16))) float f32x16;
typedef __attribute__((ext_vector_type(8))) short short8;
typedef __attribute__((ext_vector_type(4))) unsigned short u16x4;

__device__ __forceinline__ unsigned short bf16_rne(float x){
  union { float f; unsigned int u; } v; v.f = x;
  unsigned int u = v.u;
  return (unsigned short)((u + 0x7FFFu + ((u >> 16) & 1u)) >> 16);
}
__device__ __forceinline__ float bf16_f32(unsigned short h){
  union { unsigned int u; float f; } v; v.u = ((unsigned int)h) << 16;
  return v.f;
}
// 5-instr tanh: exact saturation (e->0 => -1, e->inf => +1), ~1e-6 abs err
__device__ __forceinline__ float tanh_cheap(float x){
  float e = __expf(x + x);
  return 1.0f - 2.0f * __builtin_amdgcn_rcpf(e + 1.0f);
}
__device__ __forceinline__ short8 cvt8(f32x4 a, f32x4 b){
  short8 r;
  r[0] = (short)bf16_rne(a[0]); r[1] = (short)bf16_rne(a[1]);
  r[2] = (short)bf16_rne(a[2]); r[3] = (short)bf16_rne(a[3]);
  r[4] = (short)bf16_rne(b[0]); r[5] = (short)bf16_rne(b[1]);
  r[6] = (short)bf16_rne(b[2]); r[7] = (short)bf16_rne(b[3]);
  return r;
}

// ---------------- W2 -> bf16 hi/lo split (1 MB, per call) ----------------
__global__ __launch_bounds__(256) void k_convert_w2(
    const float* __restrict__ w2, unsigned short* __restrict__ hi,
    unsigned short* __restrict__ lo){
  int i = (blockIdx.x * 256 + threadIdx.x) * 4;
  f32x4 v = *(const f32x4*)(w2 + i);
  u16x4 h, l;
  #pragma unroll
  for (int e = 0; e < 4; ++e) {
    unsigned short hb = bf16_rne(v[e]);
    h[e] = hb;
    l[e] = bf16_rne(v[e] - bf16_f32(hb));
  }
  *(u16x4*)(hi + i) = h;
  *(u16x4*)(lo + i) = l;
}

// ---------------- gates = x@Wih^T + b_ih + h0@Whh^T + b_hh ----------------
__global__ __launch_bounds__(256) void k_gates(
    const float* __restrict__ x, const float* __restrict__ h0,
    const float* __restrict__ Wih, const float* __restrict__ Whh,
    const float* __restrict__ bih, const float* __restrict__ bhh,
    float* __restrict__ gates){
  __shared__ float sx[H_], sh[H_];
  int b = blockIdx.y, t = threadIdx.x;
  sx[t] = x[b*H_ + t]; sx[t+256] = x[b*H_ + t + 256];
  sh[t] = h0[b*H_ + t]; sh[t+256] = h0[b*H_ + t + 256];
  __syncthreads();
  int j = blockIdx.x * 256 + t;
  const float* wi = Wih + j*H_;
  const float* wh = Whh + j*H_;
  float acc = bih[j] + bhh[j];
  #pragma unroll 4
  for (int k = 0; k < H_; k += 4) {
    f32x4 a = *(const f32x4*)(wi + k);
    f32x4 c = *(const f32x4*)(wh + k);
    acc += a[0]*sx[k] + a[1]*sx[k+1] + a[2]*sx[k+2] + a[3]*sx[k+3];
    acc += c[0]*sh[k] + c[1]*sh[k+1] + c[2]*sh[k+2] + c[3]*sh[k+3];
  }
  gates[b*2048 + j] = acc;
}

// ---------------- LSTM cell elementwise (exact tanh: h,c are outputs) ------
__global__ __launch_bounds__(256) void k_lstm(
    const float* __restrict__ gates, const float* __restrict__ c0,
    float* __restrict__ out_h, float* __restrict__ out_c, float* __restrict__ cc){
  int idx = blockIdx.x * 256 + threadIdx.x;   // 16384
  int b = idx >> 9, hh = idx & 511;
  const float* g = gates + b*2048;
  float gi = g[hh], gf = g[512+hh], gg = g[1024+hh], go = g[1536+hh];
  float si = 1.f/(1.f+expf(-gi));
  float sf = 1.f/(1.f+expf(-gf));
  float so = 1.f/(1.f+expf(-go));
  float c = sf * c0[idx] + si * tanhf(gg);
  float h = so * tanhf(c);
  out_h[idx] = h; out_c[idx] = c;
  cc[b*1024 + hh] = h;
}

// ---------------- q = h@W1^T + b1 ----------------
__global__ __launch_bounds__(256) void k_q(
    const float* __restrict__ cc, const float* __restrict__ W1,
    const float* __restrict__ b1, float* __restrict__ q){
  __shared__ float shh[H_];
  int b = blockIdx.y, t = threadIdx.x;
  shh[t] = cc[b*1024 + t]; shh[t+256] = cc[b*1024 + t + 256];
  __syncthreads();
  int j = blockIdx.x*256 + t;
  const float* w = W1 + j*H_;
  float acc = b1[j];
  #pragma unroll 4
  for (int k = 0; k < H_; k += 4){
    f32x4 a = *(const f32x4*)(w + k);
    acc += a[0]*shh[k] + a[1]*shh[k+1] + a[2]*shh[k+2] + a[3]*shh[k+3];
  }
  q[b*H_ + j] = acc;
}

// ---------------- scores: 64-row tile, 32x32x16 MFMA, 2-term split ---------
// 8 waves; wave owns j-slice [wave*64, wave*64+64) as 2 jt of 32; all 64 rows
// as 2 mt of 32. A = doc as single rne-bf16 (hi) in LDS, double-buffered,
// layout [row][chunk^(row&7)][8] (2-way max on both write and read).
// B = W2 split hi+lo from L2. D = Bh*Ah + Bl*Ah.
// 32x32x16 layouts (m74/m101/m214): A/B: idx=lane&31, k=(lane>>5)*8+e;
// D: row(j)=(reg&3)+8*(reg>>2)+4*(lane>>5), col(m)=lane&31.
__global__ __launch_bounds__(512, 4) void k_scores(
    const float* __restrict__ doc, const unsigned short* __restrict__ w2hi,
    const unsigned short* __restrict__ w2lo, const float* __restrict__ qv,
    const float* __restrict__ w2b, const float* __restrict__ u1,
    const int* __restrict__ mask, float* __restrict__ scores){
  __shared__ short Ah[2][MBLK][8][8];        // 16 KB
  __shared__ float2 s_qu[512];               // 4 KB  (.x = q+b2, .y = u1)
  __shared__ float s_part[8][MBLK];          // 2 KB
  int t = threadIdx.x;
  int row0 = blockIdx.x * MBLK;
  int b = row0 >> 12;
  s_qu[t] = make_float2(qv[b*512 + t] + w2b[t], u1[t]);

  // staging: thread = (row sr, 8-float group sg)
  int sr = t >> 3;            // 0..63
  int sg = t & 7;             // 0..7
  const float* dbase = doc + (((long)(row0 + sr)) << 9) + sg*8;
  int wchunk = sg ^ (sr & 7);

  int wave = t >> 6, lane = t & 63;
  int lrow = lane & 31, hi5 = lane >> 5;

  const unsigned short* pbh0 = w2hi + (wave*64 + lrow)*512 + hi5*8;
  const unsigned short* pbh1 = pbh0 + 32*512;
  const unsigned short* pbl0 = w2lo + (wave*64 + lrow)*512 + hi5*8;
  const unsigned short* pbl1 = pbl0 + 32*512;

  f32x16 acc[2][2];  // [mt][jt]
  #pragma unroll
  for (int mt = 0; mt < 2; ++mt)
    #pragma unroll
    for (int jt = 0; jt < 2; ++jt)
      #pragma unroll
      for (int e = 0; e < 16; ++e) acc[mt][jt][e] = 0.f;

  // stage step 0
  {
    f32x4 v0 = *(const f32x4*)(dbase);
    f32x4 v1 = *(const f32x4*)(dbase + 4);
    *(short8*)&Ah[0][sr][wchunk][0] = cvt8(v0, v1);
  }
  __syncthreads();

  int buf = 0;
  for (int s = 0; s < 8; ++s){
    f32x4 pf0, pf1;
    if (s < 7){
      pf0 = *(const f32x4*)(dbase + (s+1)*64);
      pf1 = *(const f32x4*)(dbase + (s+1)*64 + 4);
    }
    #pragma unroll
    for (int kt = 0; kt < 4; ++kt){
      int ko = s*64 + kt*16;
      short8 vbh0 = *(const short8*)(pbh0 + ko);
      short8 vbl0 = *(const short8*)(pbl0 + ko);
      short8 vbh1 = *(const short8*)(pbh1 + ko);
      short8 vbl1 = *(const short8*)(pbl1 + ko);
      __builtin_amdgcn_s_setprio(1);
      #pragma unroll
      for (int mt = 0; mt < 2; ++mt){
        int row = mt*32 + lrow;
        short8 a = *(const short8*)&Ah[buf][row][(kt*2 + hi5) ^ (row & 7)][0];
        acc[mt][0] = __builtin_amdgcn_mfma_f32_32x32x16_bf16(vbh0, a, acc[mt][0], 0, 0, 0);
        acc[mt][0] = __builtin_amdgcn_mfma_f32_32x32x16_bf16(vbl0, a, acc[mt][0], 0, 0, 0);
        acc[mt][1] = __builtin_amdgcn_mfma_f32_32x32x16_bf16(vbh1, a, acc[mt][1], 0, 0, 0);
        acc[mt][1] = __builtin_amdgcn_mfma_f32_32x32x16_bf16(vbl1, a, acc[mt][1], 0, 0, 0);
      }
      __builtin_amdgcn_s_setprio(0);
    }
    if (s < 7)
      *(short8*)&Ah[buf^1][sr][wchunk][0] = cvt8(pf0, pf1);
    __syncthreads();
    buf ^= 1;
  }

  // epilogue: tanh + u1-dot over this wave's 64 j's, per row
  float pm0 = 0.f, pm1 = 0.f;
  #pragma unroll
  for (int jt = 0; jt < 2; ++jt){
    #pragma unroll
    for (int r = 0; r < 16; ++r){
      int j = wave*64 + jt*32 + (r & 3) + 8*(r >> 2) + 4*hi5;
      float2 qu = s_qu[j];
      pm0 += tanh_cheap(acc[0][jt][r] + qu.x) * qu.y;
      pm1 += tanh_cheap(acc[1][jt][r] + qu.x) * qu.y;
    }
  }
  pm0 += __shfl_xor(pm0, 32);
  pm1 += __shfl_xor(pm1, 32);
  if (lane < 32){ s_part[wave][lrow] = pm0; s_part[wave][32 + lrow] = pm1; }
  __syncthreads();
  if (t < MBLK){
    float ssum = 0.f;
    #pragma unroll
    for (int w = 0; w < 8; ++w) ssum += s_part[w][t];
    int gl = row0 + t;
    scores[gl] = mask[gl] ? ssum : -INFINITY;
  }
}

// ---------------- softmax over L per row b (in place) ----------------
__global__ __launch_bounds__(256) void k_softmax(float* __restrict__ sc){
  __shared__ float red[256];
  int b = blockIdx.x, t = threadIdx.x;
  float v[16]; float m = -INFINITY;
  #pragma unroll
  for (int i = 0; i < 16; ++i){ v[i] = sc[b*4096 + i*256 + t]; m = fmaxf(m, v[i]); }
  red[t] = m; __syncthreads();
  for (int s = 128; s > 0; s >>= 1){ if (t < s) red[t] = fmaxf(red[t], red[t+s]); __syncthreads(); }
  m = red[0]; __syncthreads();
  float sum = 0.f;
  #pragma unroll
  for (int i = 0; i < 16; ++i){ v[i] = expf(v[i] - m); sum += v[i]; }
  red[t] = sum; __syncthreads();
  for (int s = 128; s > 0; s >>= 1){ if (t < s) red[t] += red[t+s]; __syncthreads(); }
  float inv = 1.f / red[0];
  #pragma unroll
  for (int i = 0; i < 16; ++i) sc[b*4096 + i*256 + t] = v[i] * inv;
}

// ---------------- context partials ----------------
#define CCH 64
__global__ __launch_bounds__(256) void k_ctx(
    const float* __restrict__ attn, const float* __restrict__ doc,
    float* __restrict__ ctxp){
  __shared__ float sa[CCH];
  int b = blockIdx.y, ch = blockIdx.x, t = threadIdx.x;
  int l0 = ch * CCH;
  if (t < CCH) sa[t] = attn[b*4096 + l0 + t];
  __syncthreads();
  const float* dp = doc + (((long)b*4096 + l0) << 9) + t*2;
  float ax = 0.f, ay = 0.f;
  #pragma unroll 4
  for (int l = 0; l < CCH; ++l){
    f32x2 d = *(const f32x2*)dp;
    float a = sa[l];
    ax += a * d[0]; ay += a * d[1];
    dp += 512;
  }
  int o = (b*64 + ch)*512 + t*2;
  ctxp[o] = ax; ctxp[o+1] = ay;
}

__global__ __launch_bounds__(256) void k_ctx_reduce(
    const float* __restrict__ ctxp, float* __restrict__ cc){
  int idx = blockIdx.x*256 + threadIdx.x;  // 16384
  int b = idx >> 9, hh = idx & 511;
  float s = 0.f;
  #pragma unroll 8
  for (int ch = 0; ch < 64; ++ch) s += ctxp[(b*64 + ch)*512 + hh];
  cc[b*1024 + 512 + hh] = s;
}

// ---------------- output = cc @ Wout^T + bout ----------------
__global__ __launch_bounds__(256) void k_out(
    const float* __restrict__ cc, const float* __restrict__ Wout,
    const float* __restrict__ bout, float* __restrict__ out){
  __shared__ float scc[32*256];
  int t = threadIdx.x, wave = t >> 6, lane = t & 63;
  int v0 = blockIdx.x * 8;
  float acc[8][8];
  #pragma unroll
  for (int v = 0; v < 8; ++v)
    #pragma unroll
    for (int bb = 0; bb < 8; ++bb) acc[v][bb] = 0.f;
  for (int kc = 0; kc < 4; ++kc){
    __syncthreads();
    for (int i = t; i < 2048; i += 256){
      int bb = i >> 6;
      int k = (i & 63) * 4;
      *(f32x4*)&scc[bb*256 + k] = *(const f32x4*)&cc[bb*1024 + kc*256 + k];
    }
    __syncthreads();
    int kl = lane * 4;
    f32x4 wv[8];
    #pragma unroll
    for (int v = 0; v < 8; ++v)
      wv[v] = *(const f32x4*)&Wout[(long)(v0 + v)*1024 + kc*256 + kl];
    #pragma unroll
    for (int bb = 0; bb < 8; ++bb){
      f32x4 c4 = *(const f32x4*)&scc[(wave*8 + bb)*256 + kl];
      #pragma unroll
      for (int v = 0; v < 8; ++v)
        acc[v][bb] += wv[v][0]*c4[0] + wv[v][1]*c4[1] + wv[v][2]*c4[2] + wv[v][3]*c4[3];
    }
  }
  #pragma unroll
  for (int v = 0; v < 8; ++v)
    #pragma unroll
    for (int bb = 0; bb < 8; ++bb){
      float a = acc[v][bb];
      a += __shfl_xor(a, 1);  a += __shfl_xor(a, 2);  a += __shfl_xor(a, 4);
      a += __shfl_xor(a, 8);  a += __shfl_xor(a, 16); a += __shfl_xor(a, 32);
      acc[v][bb] = a;
    }
  #pragma unroll
  for (int v = 0; v < 8; ++v){
    float r = acc[v][0];
    #pragma unroll
    for (int bb = 1; bb < 8; ++bb) r = (lane == bb) ? acc[v][bb] : r;
    if (lane < 8) out[(wave*8 + lane)*V_ + v0 + v] = r + bout[v0 + v];
  }
}

extern "C" void kernel_launch(void* const* d_in, const int* in_sizes, int n_in,
                              void* d_out, int out_size, void* d_ws, size_t ws_size,
                              hipStream_t stream){
  const float* x    = (const float*)d_in[0];
  const float* h0   = (const float*)d_in[1];
  const float* c0   = (const float*)d_in[2];
  const float* doc  = (const float*)d_in[3];
  const int*   mask = (const int*)d_in[4];
  const float* Wih  = (const float*)d_in[5];
  const float* Whh  = (const float*)d_in[6];
  const float* bih  = (const float*)d_in[7];
  const float* bhh  = (const float*)d_in[8];
  const float* W1   = (const float*)d_in[9];
  const float* b1   = (const float*)d_in[10];
  const float* W2   = (const float*)d_in[11];
  const float* b2   = (const float*)d_in[12];
  const float* u1   = (const float*)d_in[13];
  const float* Wo   = (const float*)d_in[14];
  const float* bo   = (const float*)d_in[15];
  float* out  = (float*)d_out;
  float* outh = out + B_*V_;
  float* outc = outh + B_*H_;

  float* ws    = (float*)d_ws;
  float* gates = ws;                  // 65536 f32
  float* q     = gates + 65536;       // 16384
  float* cc    = q + 16384;           // 32768
  float* attn  = cc + 32768;          // 131072
  float* ctxp  = attn + 131072;       // 1048576
  unsigned short* w2hi = (unsigned short*)(ctxp + 1048576); // 262144 u16
  unsigned short* w2lo = w2hi + 262144;

  hipLaunchKernelGGL(k_convert_w2, dim3(256), dim3(256), 0, stream, W2, w2hi, w2lo);
  hipLaunchKernelGGL(k_gates, dim3(8, 32), dim3(256), 0, stream, x, h0, Wih, Whh, bih, bhh, gates);
  hipLaunchKernelGGL(k_lstm, dim3(64), dim3(256), 0, stream, gates, c0, outh, outc, cc);
  hipLaunchKernelGGL(k_q, dim3(2, 32), dim3(256), 0, stream, cc, W1, b1, q);
  hipLaunchKernelGGL(k_scores, dim3(2048), dim3(512), 0, stream, doc, w2hi, w2lo, q, b2, u1, mask, attn);
  hipLaunchKernelGGL(k_softmax, dim3(32), dim3(256), 0, stream, attn);
  hipLaunchKernelGGL(k_ctx, dim3(64, 32), dim3(256), 0, stream, attn, doc, ctxp);
  hipLaunchKernelGGL(k_ctx_reduce, dim3(64), dim3(256), 0, stream, ctxp, cc);
  hipLaunchKernelGGL(k_out, dim3(4000), dim3(256), 0, stream, cc, Wo, bo, out);
}

// Round 4
// 428.777 us; speedup vs baseline: 1.2563x; 1.2563x over previous
//
#include <hip/hip_runtime.h>
#include <math.h>

#define B_  32
#define L_  4096
#define H_  512
#define V_  32000
#define MBLK 64

typedef __attribute__((ext_vector_type(4))) float f32x4;
typedef __attribute__((ext_vector_type(2))) float f32x2;
typedef __attribute__((ext_vector_type(8))) short short8;
typedef __attribute__((ext_vector_type(4))) unsigned short u16x4;

__device__ __forceinline__ unsigned short bf16_rne(float x){
  union { float f; unsigned int u; } v; v.f = x;
  unsigned int u = v.u;
  return (unsigned short)((u + 0x7FFFu + ((u >> 16) & 1u)) >> 16);
}
__device__ __forceinline__ float bf16_f32(unsigned short h){
  union { unsigned int u; float f; } v; v.u = ((unsigned int)h) << 16;
  return v.f;
}
// cheap tanh: exact saturation, ~1e-6 abs err
__device__ __forceinline__ float tanh_cheap(float x){
  float e = __expf(x + x);
  return 1.0f - 2.0f * __builtin_amdgcn_rcpf(e + 1.0f);
}
__device__ __forceinline__ short8 cvt8(f32x4 a, f32x4 b){
  short8 r;
  r[0] = (short)bf16_rne(a[0]); r[1] = (short)bf16_rne(a[1]);
  r[2] = (short)bf16_rne(a[2]); r[3] = (short)bf16_rne(a[3]);
  r[4] = (short)bf16_rne(b[0]); r[5] = (short)bf16_rne(b[1]);
  r[6] = (short)bf16_rne(b[2]); r[7] = (short)bf16_rne(b[3]);
  return r;
}

// ---------------- W2 -> bf16 hi/lo split (1 MB, per call) ----------------
__global__ __launch_bounds__(256) void k_convert_w2(
    const float* __restrict__ w2, unsigned short* __restrict__ hi,
    unsigned short* __restrict__ lo){
  int i = (blockIdx.x * 256 + threadIdx.x) * 4;
  f32x4 v = *(const f32x4*)(w2 + i);
  u16x4 h, l;
  #pragma unroll
  for (int e = 0; e < 4; ++e) {
    unsigned short hb = bf16_rne(v[e]);
    h[e] = hb;
    l[e] = bf16_rne(v[e] - bf16_f32(hb));
  }
  *(u16x4*)(hi + i) = h;
  *(u16x4*)(lo + i) = l;
}

// ---------------- gates ----------------
__global__ __launch_bounds__(256) void k_gates(
    const float* __restrict__ x, const float* __restrict__ h0,
    const float* __restrict__ Wih, const float* __restrict__ Whh,
    const float* __restrict__ bih, const float* __restrict__ bhh,
    float* __restrict__ gates){
  __shared__ float sx[H_], sh[H_];
  int b = blockIdx.y, t = threadIdx.x;
  sx[t] = x[b*H_ + t]; sx[t+256] = x[b*H_ + t + 256];
  sh[t] = h0[b*H_ + t]; sh[t+256] = h0[b*H_ + t + 256];
  __syncthreads();
  int j = blockIdx.x * 256 + t;
  const float* wi = Wih + j*H_;
  const float* wh = Whh + j*H_;
  float acc = bih[j] + bhh[j];
  #pragma unroll 4
  for (int k = 0; k < H_; k += 4) {
    f32x4 a = *(const f32x4*)(wi + k);
    f32x4 c = *(const f32x4*)(wh + k);
    acc += a[0]*sx[k] + a[1]*sx[k+1] + a[2]*sx[k+2] + a[3]*sx[k+3];
    acc += c[0]*sh[k] + c[1]*sh[k+1] + c[2]*sh[k+2] + c[3]*sh[k+3];
  }
  gates[b*2048 + j] = acc;
}

// ---------------- LSTM cell (exact tanh; also mirrors h to bf16 cc) -------
__global__ __launch_bounds__(256) void k_lstm(
    const float* __restrict__ gates, const float* __restrict__ c0,
    float* __restrict__ out_h, float* __restrict__ out_c, float* __restrict__ cc,
    unsigned short* __restrict__ ccb){
  int idx = blockIdx.x * 256 + threadIdx.x;   // 16384
  int b = idx >> 9, hh = idx & 511;
  const float* g = gates + b*2048;
  float gi = g[hh], gf = g[512+hh], gg = g[1024+hh], go = g[1536+hh];
  float si = 1.f/(1.f+expf(-gi));
  float sf = 1.f/(1.f+expf(-gf));
  float so = 1.f/(1.f+expf(-go));
  float c = sf * c0[idx] + si * tanhf(gg);
  float h = so * tanhf(c);
  out_h[idx] = h; out_c[idx] = c;
  cc[b*1024 + hh] = h;
  ccb[b*1024 + hh] = bf16_rne(h);
}

// ---------------- q = h@W1^T + b1 ----------------
__global__ __launch_bounds__(256) void k_q(
    const float* __restrict__ cc, const float* __restrict__ W1,
    const float* __restrict__ b1, float* __restrict__ q){
  __shared__ float shh[H_];
  int b = blockIdx.y, t = threadIdx.x;
  shh[t] = cc[b*1024 + t]; shh[t+256] = cc[b*1024 + t + 256];
  __syncthreads();
  int j = blockIdx.x*256 + t;
  const float* w = W1 + j*H_;
  float acc = b1[j];
  #pragma unroll 4
  for (int k = 0; k < H_; k += 4){
    f32x4 a = *(const f32x4*)(w + k);
    acc += a[0]*shh[k] + a[1]*shh[k+1] + a[2]*shh[k+2] + a[3]*shh[k+3];
  }
  q[b*H_ + j] = acc;
}

// ---------------- scores: 64-row tile, full N=512, 16x16x32, 2-term -------
// 8 waves; wave owns j-slice [w*64, w*64+64) (4 jj of 16) x all 64 rows
// (4 mt of 16). 16 independent f32x4 acc chains. A = doc bf16 in LDS, dbuf,
// [row][chunk^(row&7)][8]. B = W2 hi+lo from L2.
// D layout (validated R1/R2): j_local = (lane>>4)*4 + reg, m = lane&15.
__global__ __launch_bounds__(512, 4) void k_scores(
    const float* __restrict__ doc, const unsigned short* __restrict__ w2hi,
    const unsigned short* __restrict__ w2lo, const float* __restrict__ qv,
    const float* __restrict__ w2b, const float* __restrict__ u1,
    const int* __restrict__ mask, float* __restrict__ scores){
  __shared__ short Ah[2][MBLK][8][8];        // 16 KB
  __shared__ float2 s_qu[512];               // 4 KB
  __shared__ float s_part[8][MBLK];          // 2 KB
  int t = threadIdx.x;
  int row0 = blockIdx.x * MBLK;
  int b = row0 >> 12;
  s_qu[t] = make_float2(qv[b*512 + t] + w2b[t], u1[t]);

  int sr = t >> 3;            // 0..63 row
  int sg = t & 7;             // 0..7 k-chunk
  const float* dbase = doc + (((long)(row0 + sr)) << 9) + sg*8;
  int wchunk = sg ^ (sr & 7);

  int wave = t >> 6, lane = t & 63;
  int lrow = lane & 15, lk = lane >> 4;
  int j0 = wave * 64;
  const unsigned short* pbh = w2hi + (j0 + lrow)*512 + lk*8;
  const unsigned short* pbl = w2lo + (j0 + lrow)*512 + lk*8;

  f32x4 acc[4][4];  // [mt][jj]
  #pragma unroll
  for (int mt = 0; mt < 4; ++mt)
    #pragma unroll
    for (int jj = 0; jj < 4; ++jj)
      acc[mt][jj] = (f32x4){0.f, 0.f, 0.f, 0.f};

  { // stage step 0
    f32x4 v0 = *(const f32x4*)(dbase);
    f32x4 v1 = *(const f32x4*)(dbase + 4);
    *(short8*)&Ah[0][sr][wchunk][0] = cvt8(v0, v1);
  }
  __syncthreads();

  int buf = 0;
  for (int s = 0; s < 8; ++s){
    f32x4 pf0, pf1;
    if (s < 7){
      pf0 = *(const f32x4*)(dbase + (s+1)*64);
      pf1 = *(const f32x4*)(dbase + (s+1)*64 + 4);
    }
    #pragma unroll
    for (int ktl = 0; ktl < 2; ++ktl){
      short8 a[4];
      #pragma unroll
      for (int mt = 0; mt < 4; ++mt){
        int row = mt*16 + lrow;
        a[mt] = *(const short8*)&Ah[buf][row][(ktl*4 + lk) ^ (row & 7)][0];
      }
      int ko = s*64 + ktl*32;
      #pragma unroll
      for (int jj = 0; jj < 4; ++jj){
        short8 bh = *(const short8*)(pbh + jj*16*512 + ko);
        short8 bl = *(const short8*)(pbl + jj*16*512 + ko);
        #pragma unroll
        for (int mt = 0; mt < 4; ++mt){
          acc[mt][jj] = __builtin_amdgcn_mfma_f32_16x16x32_bf16(bh, a[mt], acc[mt][jj], 0, 0, 0);
          acc[mt][jj] = __builtin_amdgcn_mfma_f32_16x16x32_bf16(bl, a[mt], acc[mt][jj], 0, 0, 0);
        }
      }
    }
    if (s < 7)
      *(short8*)&Ah[buf^1][sr][wchunk][0] = cvt8(pf0, pf1);
    __syncthreads();
    buf ^= 1;
  }

  // epilogue: tanh + u1-dot over wave's 64 j's, per m-row
  #pragma unroll
  for (int mt = 0; mt < 4; ++mt){
    float p = 0.f;
    #pragma unroll
    for (int jj = 0; jj < 4; ++jj){
      #pragma unroll
      for (int r = 0; r < 4; ++r){
        int j = j0 + jj*16 + lk*4 + r;
        float2 qu = s_qu[j];
        p += tanh_cheap(acc[mt][jj][r] + qu.x) * qu.y;
      }
    }
    p += __shfl_xor(p, 16);
    p += __shfl_xor(p, 32);
    if (lane < 16) s_part[wave][mt*16 + lrow] = p;
  }
  __syncthreads();
  if (t < MBLK){
    float ssum = 0.f;
    #pragma unroll
    for (int w = 0; w < 8; ++w) ssum += s_part[w][t];
    int gl = row0 + t;
    scores[gl] = mask[gl] ? ssum : -INFINITY;
  }
}

// ---------------- softmax over L per row b (in place) ----------------
__global__ __launch_bounds__(256) void k_softmax(float* __restrict__ sc){
  __shared__ float red[256];
  int b = blockIdx.x, t = threadIdx.x;
  float v[16]; float m = -INFINITY;
  #pragma unroll
  for (int i = 0; i < 16; ++i){ v[i] = sc[b*4096 + i*256 + t]; m = fmaxf(m, v[i]); }
  red[t] = m; __syncthreads();
  for (int s = 128; s > 0; s >>= 1){ if (t < s) red[t] = fmaxf(red[t], red[t+s]); __syncthreads(); }
  m = red[0]; __syncthreads();
  float sum = 0.f;
  #pragma unroll
  for (int i = 0; i < 16; ++i){ v[i] = expf(v[i] - m); sum += v[i]; }
  red[t] = sum; __syncthreads();
  for (int s = 128; s > 0; s >>= 1){ if (t < s) red[t] += red[t+s]; __syncthreads(); }
  float inv = 1.f / red[0];
  #pragma unroll
  for (int i = 0; i < 16; ++i) sc[b*4096 + i*256 + t] = v[i] * inv;
}

// ---------------- context partials ----------------
#define CCH 64
__global__ __launch_bounds__(256) void k_ctx(
    const float* __restrict__ attn, const float* __restrict__ doc,
    float* __restrict__ ctxp){
  __shared__ float sa[CCH];
  int b = blockIdx.y, ch = blockIdx.x, t = threadIdx.x;
  int l0 = ch * CCH;
  if (t < CCH) sa[t] = attn[b*4096 + l0 + t];
  __syncthreads();
  const float* dp = doc + (((long)b*4096 + l0) << 9) + t*2;
  float ax = 0.f, ay = 0.f;
  #pragma unroll 4
  for (int l = 0; l < CCH; ++l){
    f32x2 d = *(const f32x2*)dp;
    float a = sa[l];
    ax += a * d[0]; ay += a * d[1];
    dp += 512;
  }
  int o = (b*64 + ch)*512 + t*2;
  ctxp[o] = ax; ctxp[o+1] = ay;
}

__global__ __launch_bounds__(256) void k_ctx_reduce(
    const float* __restrict__ ctxp, float* __restrict__ cc,
    unsigned short* __restrict__ ccb){
  int idx = blockIdx.x*256 + threadIdx.x;  // 16384
  int b = idx >> 9, hh = idx & 511;
  float s = 0.f;
  #pragma unroll 8
  for (int ch = 0; ch < 64; ++ch) s += ctxp[(b*64 + ch)*512 + hh];
  cc[b*1024 + 512 + hh] = s;
  ccb[b*1024 + 512 + hh] = bf16_rne(s);
}

// ---------------- output = cc @ Wout^T + bout, bf16 MFMA ----------------
// 500 blocks x 64 v, 256 thr (4 waves). cc bf16 tile in LDS (swizzled);
// Wout f32 read once, cvt inline. D transposed via LDS for coalesced store.
__global__ __launch_bounds__(256) void k_out(
    const unsigned short* __restrict__ ccb, const float* __restrict__ Wout,
    const float* __restrict__ bout, float* __restrict__ out){
  __shared__ short Ccb[32][128][8];      // 64 KB
  __shared__ float s_out[32][65];        // 8.3 KB
  int t = threadIdx.x, wave = t >> 6, lane = t & 63;
  int v0 = blockIdx.x * 64;
  // stage cc bf16 (32x1024) into LDS, chunk-swizzled
  #pragma unroll
  for (int i = 0; i < 16; ++i){
    int c16 = i*256 + t;               // 16B-chunk index over 4096
    int bb = c16 >> 7, ch = c16 & 127;
    int chsw = (ch & ~7) | ((ch & 7) ^ (bb & 7));
    *(short8*)&Ccb[bb][chsw][0] = *(const short8*)(ccb + c16*8);
  }
  __syncthreads();

  int lrow = lane & 15, lk = lane >> 4;
  int vrow = v0 + wave*16 + lrow;
  const float* wptr = Wout + (long)vrow*1024 + lk*8;
  f32x4 acc[2];
  acc[0] = (f32x4){0.f,0.f,0.f,0.f};
  acc[1] = (f32x4){0.f,0.f,0.f,0.f};
  int sw = lrow & 7;   // same for lrow and lrow+16
  #pragma unroll 4
  for (int ks = 0; ks < 32; ++ks){
    f32x4 w0 = *(const f32x4*)(wptr + ks*32);
    f32x4 w1 = *(const f32x4*)(wptr + ks*32 + 4);
    short8 bfrag = cvt8(w0, w1);
    int ch = ks*4 + lk;
    int chsw = (ch & ~7) | ((ch & 7) ^ sw);
    short8 a0 = *(const short8*)&Ccb[lrow][chsw][0];
    short8 a1 = *(const short8*)&Ccb[16 + lrow][chsw][0];
    acc[0] = __builtin_amdgcn_mfma_f32_16x16x32_bf16(bfrag, a0, acc[0], 0, 0, 0);
    acc[1] = __builtin_amdgcn_mfma_f32_16x16x32_bf16(bfrag, a1, acc[1], 0, 0, 0);
  }
  // D: j_local = lk*4+r (v), m = lrow (b)
  #pragma unroll
  for (int mt = 0; mt < 2; ++mt)
    #pragma unroll
    for (int r = 0; r < 4; ++r)
      s_out[mt*16 + lrow][wave*16 + lk*4 + r] = acc[mt][r];
  __syncthreads();
  int vcol = t & 63, bq = t >> 6;
  float bo = bout[v0 + vcol];
  #pragma unroll
  for (int bb = 0; bb < 8; ++bb){
    int brow = bb*4 + bq;
    out[(long)brow*V_ + v0 + vcol] = s_out[brow][vcol] + bo;
  }
}

extern "C" void kernel_launch(void* const* d_in, const int* in_sizes, int n_in,
                              void* d_out, int out_size, void* d_ws, size_t ws_size,
                              hipStream_t stream){
  const float* x    = (const float*)d_in[0];
  const float* h0   = (const float*)d_in[1];
  const float* c0   = (const float*)d_in[2];
  const float* doc  = (const float*)d_in[3];
  const int*   mask = (const int*)d_in[4];
  const float* Wih  = (const float*)d_in[5];
  const float* Whh  = (const float*)d_in[6];
  const float* bih  = (const float*)d_in[7];
  const float* bhh  = (const float*)d_in[8];
  const float* W1   = (const float*)d_in[9];
  const float* b1   = (const float*)d_in[10];
  const float* W2   = (const float*)d_in[11];
  const float* b2   = (const float*)d_in[12];
  const float* u1   = (const float*)d_in[13];
  const float* Wo   = (const float*)d_in[14];
  const float* bo   = (const float*)d_in[15];
  float* out  = (float*)d_out;
  float* outh = out + B_*V_;
  float* outc = outh + B_*H_;

  float* ws    = (float*)d_ws;
  float* gates = ws;                  // 65536 f32
  float* q     = gates + 65536;       // 16384
  float* cc    = q + 16384;           // 32768
  float* attn  = cc + 32768;          // 131072
  float* ctxp  = attn + 131072;       // 1048576
  unsigned short* w2hi = (unsigned short*)(ctxp + 1048576); // 262144 u16
  unsigned short* w2lo = w2hi + 262144;                      // 262144 u16
  unsigned short* ccb  = w2lo + 262144;                      // 32768 u16

  hipLaunchKernelGGL(k_convert_w2, dim3(256), dim3(256), 0, stream, W2, w2hi, w2lo);
  hipLaunchKernelGGL(k_gates, dim3(8, 32), dim3(256), 0, stream, x, h0, Wih, Whh, bih, bhh, gates);
  hipLaunchKernelGGL(k_lstm, dim3(64), dim3(256), 0, stream, gates, c0, outh, outc, cc, ccb);
  hipLaunchKernelGGL(k_q, dim3(2, 32), dim3(256), 0, stream, cc, W1, b1, q);
  hipLaunchKernelGGL(k_scores, dim3(2048), dim3(512), 0, stream, doc, w2hi, w2lo, q, b2, u1, mask, attn);
  hipLaunchKernelGGL(k_softmax, dim3(32), dim3(256), 0, stream, attn);
  hipLaunchKernelGGL(k_ctx, dim3(64, 32), dim3(256), 0, stream, attn, doc, ctxp);
  hipLaunchKernelGGL(k_ctx_reduce, dim3(64), dim3(256), 0, stream, ctxp, cc, ccb);
  hipLaunchKernelGGL(k_out, dim3(500), dim3(256), 0, stream, ccb, Wo, bo, out);
}

// Round 5
// 343.775 us; speedup vs baseline: 1.5669x; 1.2473x over previous
//
#include <hip/hip_runtime.h>
#include <hip/hip_bf16.h>
#include <math.h>

#define B_  32
#define L_  4096
#define H_  512
#define V_  32000
#define MBLK 128

typedef __attribute__((ext_vector_type(4))) float f32x4;
typedef __attribute__((ext_vector_type(2))) float f32x2;
typedef __attribute__((ext_vector_type(8))) short short8;
typedef __attribute__((ext_vector_type(4))) unsigned short u16x4;

__device__ __forceinline__ unsigned short bf16_rne(float x){
  union { float f; unsigned int u; } v; v.f = x;
  unsigned int u = v.u;
  return (unsigned short)((u + 0x7FFFu + ((u >> 16) & 1u)) >> 16);
}
__device__ __forceinline__ float bf16_f32(unsigned short h){
  union { unsigned int u; float f; } v; v.u = ((unsigned int)h) << 16;
  return v.f;
}
// cheap tanh: exact saturation, ~1e-6 abs err
__device__ __forceinline__ float tanh_cheap(float x){
  float e = __expf(x + x);
  return 1.0f - 2.0f * __builtin_amdgcn_rcpf(e + 1.0f);
}
// packed f32x8 -> bf16x8 via v_cvt_pk_bf16_f32
__device__ __forceinline__ short8 cvt8(f32x4 a, f32x4 b){
  union { __hip_bfloat162 h[4]; short8 s; } u;
  u.h[0] = __float22bfloat162_rn(make_float2(a[0], a[1]));
  u.h[1] = __float22bfloat162_rn(make_float2(a[2], a[3]));
  u.h[2] = __float22bfloat162_rn(make_float2(b[0], b[1]));
  u.h[3] = __float22bfloat162_rn(make_float2(b[2], b[3]));
  return u.s;
}

// ---------------- W2 -> bf16 hi/lo split (1 MB, per call) ----------------
__global__ __launch_bounds__(256) void k_convert_w2(
    const float* __restrict__ w2, unsigned short* __restrict__ hi,
    unsigned short* __restrict__ lo){
  int i = (blockIdx.x * 256 + threadIdx.x) * 4;
  f32x4 v = *(const f32x4*)(w2 + i);
  u16x4 h, l;
  #pragma unroll
  for (int e = 0; e < 4; ++e) {
    unsigned short hb = bf16_rne(v[e]);
    h[e] = hb;
    l[e] = bf16_rne(v[e] - bf16_f32(hb));
  }
  *(u16x4*)(hi + i) = h;
  *(u16x4*)(lo + i) = l;
}

// ---------------- gates ----------------
__global__ __launch_bounds__(256) void k_gates(
    const float* __restrict__ x, const float* __restrict__ h0,
    const float* __restrict__ Wih, const float* __restrict__ Whh,
    const float* __restrict__ bih, const float* __restrict__ bhh,
    float* __restrict__ gates){
  __shared__ float sx[H_], sh[H_];
  int b = blockIdx.y, t = threadIdx.x;
  sx[t] = x[b*H_ + t]; sx[t+256] = x[b*H_ + t + 256];
  sh[t] = h0[b*H_ + t]; sh[t+256] = h0[b*H_ + t + 256];
  __syncthreads();
  int j = blockIdx.x * 256 + t;
  const float* wi = Wih + j*H_;
  const float* wh = Whh + j*H_;
  float acc = bih[j] + bhh[j];
  #pragma unroll 4
  for (int k = 0; k < H_; k += 4) {
    f32x4 a = *(const f32x4*)(wi + k);
    f32x4 c = *(const f32x4*)(wh + k);
    acc += a[0]*sx[k] + a[1]*sx[k+1] + a[2]*sx[k+2] + a[3]*sx[k+3];
    acc += c[0]*sh[k] + c[1]*sh[k+1] + c[2]*sh[k+2] + c[3]*sh[k+3];
  }
  gates[b*2048 + j] = acc;
}

// ---------------- LSTM cell (exact tanh; mirrors h into f32 cc + bf16 ccb) -
__global__ __launch_bounds__(256) void k_lstm(
    const float* __restrict__ gates, const float* __restrict__ c0,
    float* __restrict__ out_h, float* __restrict__ out_c, float* __restrict__ cc,
    unsigned short* __restrict__ ccb){
  int idx = blockIdx.x * 256 + threadIdx.x;   // 16384
  int b = idx >> 9, hh = idx & 511;
  const float* g = gates + b*2048;
  float gi = g[hh], gf = g[512+hh], gg = g[1024+hh], go = g[1536+hh];
  float si = 1.f/(1.f+expf(-gi));
  float sf = 1.f/(1.f+expf(-gf));
  float so = 1.f/(1.f+expf(-go));
  float c = sf * c0[idx] + si * tanhf(gg);
  float h = so * tanhf(c);
  out_h[idx] = h; out_c[idx] = c;
  cc[b*1024 + hh] = h;
  ccb[b*1024 + hh] = bf16_rne(h);
}

// ---------------- q = h@W1^T + b1 ----------------
__global__ __launch_bounds__(256) void k_q(
    const float* __restrict__ cc, const float* __restrict__ W1,
    const float* __restrict__ b1, float* __restrict__ q){
  __shared__ float shh[H_];
  int b = blockIdx.y, t = threadIdx.x;
  shh[t] = cc[b*1024 + t]; shh[t+256] = cc[b*1024 + t + 256];
  __syncthreads();
  int j = blockIdx.x*256 + t;
  const float* w = W1 + j*H_;
  float acc = b1[j];
  #pragma unroll 4
  for (int k = 0; k < H_; k += 4){
    f32x4 a = *(const f32x4*)(w + k);
    acc += a[0]*shh[k] + a[1]*shh[k+1] + a[2]*shh[k+2] + a[3]*shh[k+3];
  }
  q[b*H_ + j] = acc;
}

// ---------------- scores: 128-row tile, full N=512, 16x16x32, 2-term -------
// 8 waves; wave owns j-slice [w*64,w*64+64) (4 jj of 16) x all 128 rows
// (8 mt of 16). acc = 32 f32x4 = 128 AGPR; launch_bounds(512,2) -> 256-reg
// budget, no spills. LDS A [row][chunk^(row&7)][8] dbuf, conflict-free.
// Per ktl: all 32 hi-MFMAs then all 32 lo-MFMAs (32-deep indep chains).
__global__ __launch_bounds__(512, 2) void k_scores(
    const float* __restrict__ doc, const unsigned short* __restrict__ w2hi,
    const unsigned short* __restrict__ w2lo, const float* __restrict__ qv,
    const float* __restrict__ w2b, const float* __restrict__ u1,
    const int* __restrict__ mask, float* __restrict__ scores){
  __shared__ short Ah[2][MBLK][8][8];        // 32 KB
  __shared__ float2 s_qu[512];               // 4 KB
  __shared__ float s_part[8][MBLK];          // 4 KB
  int t = threadIdx.x;
  int row0 = blockIdx.x * MBLK;
  int b = row0 >> 12;
  s_qu[t] = make_float2(qv[b*512 + t] + w2b[t], u1[t]);

  // staging: thread = (row sr = t>>2, 16-float group sg = t&3)
  int sr = t >> 2;
  int sg = t & 3;
  const float* dbase = doc + (((long)(row0 + sr)) << 9) + sg*16;
  int wc0 = (2*sg)     ^ (sr & 7);
  int wc1 = (2*sg + 1) ^ (sr & 7);

  int wave = t >> 6, lane = t & 63;
  int lrow = lane & 15, lk = lane >> 4;
  int sw = lrow & 7;
  int j0 = wave * 64;
  const unsigned short* pbh = w2hi + (j0 + lrow)*512 + lk*8;
  const unsigned short* pbl = w2lo + (j0 + lrow)*512 + lk*8;

  f32x4 acc[8][4];  // [mt][jj]
  #pragma unroll
  for (int mt = 0; mt < 8; ++mt)
    #pragma unroll
    for (int jj = 0; jj < 4; ++jj)
      acc[mt][jj] = (f32x4){0.f, 0.f, 0.f, 0.f};

  { // stage step 0
    f32x4 v0 = *(const f32x4*)(dbase);
    f32x4 v1 = *(const f32x4*)(dbase + 4);
    f32x4 v2 = *(const f32x4*)(dbase + 8);
    f32x4 v3 = *(const f32x4*)(dbase + 12);
    *(short8*)&Ah[0][sr][wc0][0] = cvt8(v0, v1);
    *(short8*)&Ah[0][sr][wc1][0] = cvt8(v2, v3);
  }
  __syncthreads();

  int buf = 0;
  for (int s = 0; s < 8; ++s){
    f32x4 pf0, pf1, pf2, pf3;
    if (s < 7){
      const float* p = dbase + (s+1)*64;
      pf0 = *(const f32x4*)(p);
      pf1 = *(const f32x4*)(p + 4);
      pf2 = *(const f32x4*)(p + 8);
      pf3 = *(const f32x4*)(p + 12);
    }
    #pragma unroll
    for (int ktl = 0; ktl < 2; ++ktl){
      short8 a[8];
      #pragma unroll
      for (int mt = 0; mt < 8; ++mt)
        a[mt] = *(const short8*)&Ah[buf][mt*16 + lrow][(ktl*4 + lk) ^ sw][0];
      int ko = s*64 + ktl*32;
      short8 bh[4], bl[4];
      #pragma unroll
      for (int jj = 0; jj < 4; ++jj){
        bh[jj] = *(const short8*)(pbh + jj*8192 + ko);
        bl[jj] = *(const short8*)(pbl + jj*8192 + ko);
      }
      #pragma unroll
      for (int jj = 0; jj < 4; ++jj)
        #pragma unroll
        for (int mt = 0; mt < 8; ++mt)
          acc[mt][jj] = __builtin_amdgcn_mfma_f32_16x16x32_bf16(bh[jj], a[mt], acc[mt][jj], 0, 0, 0);
      #pragma unroll
      for (int jj = 0; jj < 4; ++jj)
        #pragma unroll
        for (int mt = 0; mt < 8; ++mt)
          acc[mt][jj] = __builtin_amdgcn_mfma_f32_16x16x32_bf16(bl[jj], a[mt], acc[mt][jj], 0, 0, 0);
    }
    if (s < 7){
      *(short8*)&Ah[buf^1][sr][wc0][0] = cvt8(pf0, pf1);
      *(short8*)&Ah[buf^1][sr][wc1][0] = cvt8(pf2, pf3);
    }
    __syncthreads();
    buf ^= 1;
  }

  // epilogue: tanh + u1-dot over wave's 64 j's, per m-row
  #pragma unroll
  for (int mt = 0; mt < 8; ++mt){
    float p = 0.f;
    #pragma unroll
    for (int jj = 0; jj < 4; ++jj){
      #pragma unroll
      for (int r = 0; r < 4; ++r){
        int j = j0 + jj*16 + lk*4 + r;
        float2 qu = s_qu[j];
        p += tanh_cheap(acc[mt][jj][r] + qu.x) * qu.y;
      }
    }
    p += __shfl_xor(p, 16);
    p += __shfl_xor(p, 32);
    if (lane < 16) s_part[wave][mt*16 + lrow] = p;
  }
  __syncthreads();
  if (t < MBLK){
    float ssum = 0.f;
    #pragma unroll
    for (int w = 0; w < 8; ++w) ssum += s_part[w][t];
    int gl = row0 + t;
    scores[gl] = mask[gl] ? ssum : -INFINITY;
  }
}

// ---------------- softmax over L per row b (in place) ----------------
__global__ __launch_bounds__(256) void k_softmax(float* __restrict__ sc){
  __shared__ float red[256];
  int b = blockIdx.x, t = threadIdx.x;
  float v[16]; float m = -INFINITY;
  #pragma unroll
  for (int i = 0; i < 16; ++i){ v[i] = sc[b*4096 + i*256 + t]; m = fmaxf(m, v[i]); }
  red[t] = m; __syncthreads();
  for (int s = 128; s > 0; s >>= 1){ if (t < s) red[t] = fmaxf(red[t], red[t+s]); __syncthreads(); }
  m = red[0]; __syncthreads();
  float sum = 0.f;
  #pragma unroll
  for (int i = 0; i < 16; ++i){ v[i] = expf(v[i] - m); sum += v[i]; }
  red[t] = sum; __syncthreads();
  for (int s = 128; s > 0; s >>= 1){ if (t < s) red[t] += red[t+s]; __syncthreads(); }
  float inv = 1.f / red[0];
  #pragma unroll
  for (int i = 0; i < 16; ++i) sc[b*4096 + i*256 + t] = v[i] * inv;
}

// ---------------- context partials ----------------
#define CCH 64
__global__ __launch_bounds__(256) void k_ctx(
    const float* __restrict__ attn, const float* __restrict__ doc,
    float* __restrict__ ctxp){
  __shared__ float sa[CCH];
  int b = blockIdx.y, ch = blockIdx.x, t = threadIdx.x;
  int l0 = ch * CCH;
  if (t < CCH) sa[t] = attn[b*4096 + l0 + t];
  __syncthreads();
  const float* dp = doc + (((long)b*4096 + l0) << 9) + t*2;
  float ax = 0.f, ay = 0.f;
  #pragma unroll 4
  for (int l = 0; l < CCH; ++l){
    f32x2 d = *(const f32x2*)dp;
    float a = sa[l];
    ax += a * d[0]; ay += a * d[1];
    dp += 512;
  }
  int o = (b*64 + ch)*512 + t*2;
  ctxp[o] = ax; ctxp[o+1] = ay;
}

__global__ __launch_bounds__(256) void k_ctx_reduce(
    const float* __restrict__ ctxp, float* __restrict__ cc,
    unsigned short* __restrict__ ccb){
  int idx = blockIdx.x*256 + threadIdx.x;  // 16384
  int b = idx >> 9, hh = idx & 511;
  float s = 0.f;
  #pragma unroll 8
  for (int ch = 0; ch < 64; ++ch) s += ctxp[(b*64 + ch)*512 + hh];
  cc[b*1024 + 512 + hh] = s;
  ccb[b*1024 + 512 + hh] = bf16_rne(s);
}

// ---------------- output = cc @ Wout^T + bout, bf16 MFMA ----------------
// 500 blocks x 64 v, 256 thr (4 waves). cc bf16 tile in LDS (swizzled);
// Wout f32 streamed with next-iter prefetch, pk-cvt inline.
__global__ __launch_bounds__(256) void k_out(
    const unsigned short* __restrict__ ccb, const float* __restrict__ Wout,
    const float* __restrict__ bout, float* __restrict__ out){
  __shared__ short Ccb[32][128][8];      // 64 KB
  __shared__ float s_out[32][65];        // 8.3 KB
  int t = threadIdx.x, wave = t >> 6, lane = t & 63;
  int v0 = blockIdx.x * 64;
  #pragma unroll
  for (int i = 0; i < 16; ++i){
    int c16 = i*256 + t;               // 16B-chunk index over 4096
    int bb = c16 >> 7, ch = c16 & 127;
    int chsw = (ch & ~7) | ((ch & 7) ^ (bb & 7));
    *(short8*)&Ccb[bb][chsw][0] = *(const short8*)(ccb + c16*8);
  }
  __syncthreads();

  int lrow = lane & 15, lk = lane >> 4;
  int vrow = v0 + wave*16 + lrow;
  const float* wptr = Wout + (long)vrow*1024 + lk*8;
  f32x4 acc[2];
  acc[0] = (f32x4){0.f,0.f,0.f,0.f};
  acc[1] = (f32x4){0.f,0.f,0.f,0.f};
  int sw = lrow & 7;
  f32x4 w0 = *(const f32x4*)(wptr);
  f32x4 w1 = *(const f32x4*)(wptr + 4);
  #pragma unroll 4
  for (int ks = 0; ks < 32; ++ks){
    f32x4 nw0, nw1;
    if (ks < 31){
      nw0 = *(const f32x4*)(wptr + (ks+1)*32);
      nw1 = *(const f32x4*)(wptr + (ks+1)*32 + 4);
    }
    short8 bfrag = cvt8(w0, w1);
    int ch = ks*4 + lk;
    int chsw = (ch & ~7) | ((ch & 7) ^ sw);
    short8 a0 = *(const short8*)&Ccb[lrow][chsw][0];
    short8 a1 = *(const short8*)&Ccb[16 + lrow][chsw][0];
    acc[0] = __builtin_amdgcn_mfma_f32_16x16x32_bf16(bfrag, a0, acc[0], 0, 0, 0);
    acc[1] = __builtin_amdgcn_mfma_f32_16x16x32_bf16(bfrag, a1, acc[1], 0, 0, 0);
    w0 = nw0; w1 = nw1;
  }
  #pragma unroll
  for (int mt = 0; mt < 2; ++mt)
    #pragma unroll
    for (int r = 0; r < 4; ++r)
      s_out[mt*16 + lrow][wave*16 + lk*4 + r] = acc[mt][r];
  __syncthreads();
  int vcol = t & 63, bq = t >> 6;
  float bo = bout[v0 + vcol];
  #pragma unroll
  for (int bb = 0; bb < 8; ++bb){
    int brow = bb*4 + bq;
    out[(long)brow*V_ + v0 + vcol] = s_out[brow][vcol] + bo;
  }
}

extern "C" void kernel_launch(void* const* d_in, const int* in_sizes, int n_in,
                              void* d_out, int out_size, void* d_ws, size_t ws_size,
                              hipStream_t stream){
  const float* x    = (const float*)d_in[0];
  const float* h0   = (const float*)d_in[1];
  const float* c0   = (const float*)d_in[2];
  const float* doc  = (const float*)d_in[3];
  const int*   mask = (const int*)d_in[4];
  const float* Wih  = (const float*)d_in[5];
  const float* Whh  = (const float*)d_in[6];
  const float* bih  = (const float*)d_in[7];
  const float* bhh  = (const float*)d_in[8];
  const float* W1   = (const float*)d_in[9];
  const float* b1   = (const float*)d_in[10];
  const float* W2   = (const float*)d_in[11];
  const float* b2   = (const float*)d_in[12];
  const float* u1   = (const float*)d_in[13];
  const float* Wo   = (const float*)d_in[14];
  const float* bo   = (const float*)d_in[15];
  float* out  = (float*)d_out;
  float* outh = out + B_*V_;
  float* outc = outh + B_*H_;

  float* ws    = (float*)d_ws;
  float* gates = ws;                  // 65536 f32
  float* q     = gates + 65536;       // 16384
  float* cc    = q + 16384;           // 32768
  float* attn  = cc + 32768;          // 131072
  float* ctxp  = attn + 131072;       // 1048576
  unsigned short* w2hi = (unsigned short*)(ctxp + 1048576); // 262144 u16
  unsigned short* w2lo = w2hi + 262144;                      // 262144 u16
  unsigned short* ccb  = w2lo + 262144;                      // 32768 u16

  hipLaunchKernelGGL(k_convert_w2, dim3(256), dim3(256), 0, stream, W2, w2hi, w2lo);
  hipLaunchKernelGGL(k_gates, dim3(8, 32), dim3(256), 0, stream, x, h0, Wih, Whh, bih, bhh, gates);
  hipLaunchKernelGGL(k_lstm, dim3(64), dim3(256), 0, stream, gates, c0, outh, outc, cc, ccb);
  hipLaunchKernelGGL(k_q, dim3(2, 32), dim3(256), 0, stream, cc, W1, b1, q);
  hipLaunchKernelGGL(k_scores, dim3(1024), dim3(512), 0, stream, doc, w2hi, w2lo, q, b2, u1, mask, attn);
  hipLaunchKernelGGL(k_softmax, dim3(32), dim3(256), 0, stream, attn);
  hipLaunchKernelGGL(k_ctx, dim3(64, 32), dim3(256), 0, stream, attn, doc, ctxp);
  hipLaunchKernelGGL(k_ctx_reduce, dim3(64), dim3(256), 0, stream, ctxp, cc, ccb);
  hipLaunchKernelGGL(k_out, dim3(500), dim3(256), 0, stream, ccb, Wo, bo, out);
}

// Round 6
// 272.593 us; speedup vs baseline: 1.9760x; 1.2611x over previous
//
#include <hip/hip_runtime.h>
#include <hip/hip_bf16.h>
#include <math.h>

#define B_  32
#define L_  4096
#define H_  512
#define V_  32000
#define MBLK 128

typedef __attribute__((ext_vector_type(4))) float f32x4;
typedef __attribute__((ext_vector_type(2))) float f32x2;
typedef __attribute__((ext_vector_type(8))) short short8;
typedef __attribute__((ext_vector_type(4))) unsigned short u16x4;

__device__ __forceinline__ unsigned short bf16_rne(float x){
  union { float f; unsigned int u; } v; v.f = x;
  unsigned int u = v.u;
  return (unsigned short)((u + 0x7FFFu + ((u >> 16) & 1u)) >> 16);
}
__device__ __forceinline__ float bf16_f32(unsigned short h){
  union { unsigned int u; float f; } v; v.u = ((unsigned int)h) << 16;
  return v.f;
}
// cheap tanh: exact saturation, ~1e-6 abs err
__device__ __forceinline__ float tanh_cheap(float x){
  float e = __expf(x + x);
  return 1.0f - 2.0f * __builtin_amdgcn_rcpf(e + 1.0f);
}
// packed f32x8 -> bf16x8 via v_cvt_pk_bf16_f32
__device__ __forceinline__ short8 cvt8(f32x4 a, f32x4 b){
  union { __hip_bfloat162 h[4]; short8 s; } u;
  u.h[0] = __float22bfloat162_rn(make_float2(a[0], a[1]));
  u.h[1] = __float22bfloat162_rn(make_float2(a[2], a[3]));
  u.h[2] = __float22bfloat162_rn(make_float2(b[0], b[1]));
  u.h[3] = __float22bfloat162_rn(make_float2(b[2], b[3]));
  return u.s;
}

// ---------------- W2 -> bf16 (512 KB, per call) ----------------
__global__ __launch_bounds__(256) void k_convert_w2(
    const float* __restrict__ w2, unsigned short* __restrict__ hi){
  int i = (blockIdx.x * 256 + threadIdx.x) * 4;
  f32x4 v = *(const f32x4*)(w2 + i);
  u16x4 h;
  #pragma unroll
  for (int e = 0; e < 4; ++e) h[e] = bf16_rne(v[e]);
  *(u16x4*)(hi + i) = h;
}

// ---------------- gates ----------------
__global__ __launch_bounds__(256) void k_gates(
    const float* __restrict__ x, const float* __restrict__ h0,
    const float* __restrict__ Wih, const float* __restrict__ Whh,
    const float* __restrict__ bih, const float* __restrict__ bhh,
    float* __restrict__ gates){
  __shared__ float sx[H_], sh[H_];
  int b = blockIdx.y, t = threadIdx.x;
  sx[t] = x[b*H_ + t]; sx[t+256] = x[b*H_ + t + 256];
  sh[t] = h0[b*H_ + t]; sh[t+256] = h0[b*H_ + t + 256];
  __syncthreads();
  int j = blockIdx.x * 256 + t;
  const float* wi = Wih + j*H_;
  const float* wh = Whh + j*H_;
  float acc = bih[j] + bhh[j];
  #pragma unroll 4
  for (int k = 0; k < H_; k += 4) {
    f32x4 a = *(const f32x4*)(wi + k);
    f32x4 c = *(const f32x4*)(wh + k);
    acc += a[0]*sx[k] + a[1]*sx[k+1] + a[2]*sx[k+2] + a[3]*sx[k+3];
    acc += c[0]*sh[k] + c[1]*sh[k+1] + c[2]*sh[k+2] + c[3]*sh[k+3];
  }
  gates[b*2048 + j] = acc;
}

// ---------------- LSTM cell (exact tanh; mirrors h into f32 cc + bf16 ccb) -
__global__ __launch_bounds__(256) void k_lstm(
    const float* __restrict__ gates, const float* __restrict__ c0,
    float* __restrict__ out_h, float* __restrict__ out_c, float* __restrict__ cc,
    unsigned short* __restrict__ ccb){
  int idx = blockIdx.x * 256 + threadIdx.x;   // 16384
  int b = idx >> 9, hh = idx & 511;
  const float* g = gates + b*2048;
  float gi = g[hh], gf = g[512+hh], gg = g[1024+hh], go = g[1536+hh];
  float si = 1.f/(1.f+expf(-gi));
  float sf = 1.f/(1.f+expf(-gf));
  float so = 1.f/(1.f+expf(-go));
  float c = sf * c0[idx] + si * tanhf(gg);
  float h = so * tanhf(c);
  out_h[idx] = h; out_c[idx] = c;
  cc[b*1024 + hh] = h;
  ccb[b*1024 + hh] = bf16_rne(h);
}

// ---------------- q = h@W1^T + b1 ----------------
__global__ __launch_bounds__(256) void k_q(
    const float* __restrict__ cc, const float* __restrict__ W1,
    const float* __restrict__ b1, float* __restrict__ q){
  __shared__ float shh[H_];
  int b = blockIdx.y, t = threadIdx.x;
  shh[t] = cc[b*1024 + t]; shh[t+256] = cc[b*1024 + t + 256];
  __syncthreads();
  int j = blockIdx.x*256 + t;
  const float* w = W1 + j*H_;
  float acc = b1[j];
  #pragma unroll 4
  for (int k = 0; k < H_; k += 4){
    f32x4 a = *(const f32x4*)(w + k);
    acc += a[0]*shh[k] + a[1]*shh[k+1] + a[2]*shh[k+2] + a[3]*shh[k+3];
  }
  q[b*H_ + j] = acc;
}

// ---------------- scores: 128-row tile, full N=512, 16x16x32, 1-term bf16 --
// 8 waves; wave owns j-slice [w*64,w*64+64) (4 jj of 16) x all 128 rows
// (8 mt of 16). acc = 32 f32x4 = 128 AGPR. All 8 B-frags loaded upfront
// per K-step (deep MLP). LDS A [row][chunk^(row&7)][8] dbuf, conflict-free.
__global__ __launch_bounds__(512, 2) void k_scores(
    const float* __restrict__ doc, const unsigned short* __restrict__ w2hi,
    const float* __restrict__ qv,
    const float* __restrict__ w2b, const float* __restrict__ u1,
    const int* __restrict__ mask, float* __restrict__ scores){
  __shared__ short Ah[2][MBLK][8][8];        // 32 KB
  __shared__ float2 s_qu[512];               // 4 KB
  __shared__ float s_part[8][MBLK];          // 4 KB
  int t = threadIdx.x;
  int row0 = blockIdx.x * MBLK;
  int b = row0 >> 12;
  s_qu[t] = make_float2(qv[b*512 + t] + w2b[t], u1[t]);

  // staging: thread = (row sr = t>>2, 16-float group sg = t&3)
  int sr = t >> 2;
  int sg = t & 3;
  const float* dbase = doc + (((long)(row0 + sr)) << 9) + sg*16;
  int wc0 = (2*sg)     ^ (sr & 7);
  int wc1 = (2*sg + 1) ^ (sr & 7);

  int wave = t >> 6, lane = t & 63;
  int lrow = lane & 15, lk = lane >> 4;
  int sw = lrow & 7;
  int j0 = wave * 64;
  const unsigned short* pbh = w2hi + (j0 + lrow)*512 + lk*8;

  f32x4 acc[8][4];  // [mt][jj]
  #pragma unroll
  for (int mt = 0; mt < 8; ++mt)
    #pragma unroll
    for (int jj = 0; jj < 4; ++jj)
      acc[mt][jj] = (f32x4){0.f, 0.f, 0.f, 0.f};

  { // stage step 0
    f32x4 v0 = *(const f32x4*)(dbase);
    f32x4 v1 = *(const f32x4*)(dbase + 4);
    f32x4 v2 = *(const f32x4*)(dbase + 8);
    f32x4 v3 = *(const f32x4*)(dbase + 12);
    *(short8*)&Ah[0][sr][wc0][0] = cvt8(v0, v1);
    *(short8*)&Ah[0][sr][wc1][0] = cvt8(v2, v3);
  }
  __syncthreads();

  int buf = 0;
  for (int s = 0; s < 8; ++s){
    // B fragments for the whole K-step (both ktl), issued together
    short8 bh[8];
    {
      int ko = s*64;
      #pragma unroll
      for (int jj = 0; jj < 4; ++jj){
        bh[jj]   = *(const short8*)(pbh + jj*8192 + ko);
        bh[4+jj] = *(const short8*)(pbh + jj*8192 + ko + 32);
      }
    }
    // doc prefetch for next step
    f32x4 pf0, pf1, pf2, pf3;
    if (s < 7){
      const float* p = dbase + (s+1)*64;
      pf0 = *(const f32x4*)(p);
      pf1 = *(const f32x4*)(p + 4);
      pf2 = *(const f32x4*)(p + 8);
      pf3 = *(const f32x4*)(p + 12);
    }
    #pragma unroll
    for (int ktl = 0; ktl < 2; ++ktl){
      short8 a[8];
      #pragma unroll
      for (int mt = 0; mt < 8; ++mt)
        a[mt] = *(const short8*)&Ah[buf][mt*16 + lrow][(ktl*4 + lk) ^ sw][0];
      #pragma unroll
      for (int jj = 0; jj < 4; ++jj)
        #pragma unroll
        for (int mt = 0; mt < 8; ++mt)
          acc[mt][jj] = __builtin_amdgcn_mfma_f32_16x16x32_bf16(bh[ktl*4 + jj], a[mt], acc[mt][jj], 0, 0, 0);
    }
    if (s < 7){
      *(short8*)&Ah[buf^1][sr][wc0][0] = cvt8(pf0, pf1);
      *(short8*)&Ah[buf^1][sr][wc1][0] = cvt8(pf2, pf3);
    }
    __syncthreads();
    buf ^= 1;
  }

  // epilogue: tanh + u1-dot over wave's 64 j's, per m-row
  #pragma unroll
  for (int mt = 0; mt < 8; ++mt){
    float p = 0.f;
    #pragma unroll
    for (int jj = 0; jj < 4; ++jj){
      #pragma unroll
      for (int r = 0; r < 4; ++r){
        int j = j0 + jj*16 + lk*4 + r;
        float2 qu = s_qu[j];
        p += tanh_cheap(acc[mt][jj][r] + qu.x) * qu.y;
      }
    }
    p += __shfl_xor(p, 16);
    p += __shfl_xor(p, 32);
    if (lane < 16) s_part[wave][mt*16 + lrow] = p;
  }
  __syncthreads();
  if (t < MBLK){
    float ssum = 0.f;
    #pragma unroll
    for (int w = 0; w < 8; ++w) ssum += s_part[w][t];
    int gl = row0 + t;
    scores[gl] = mask[gl] ? ssum : -INFINITY;
  }
}

// ---------------- softmax over L per row b (in place) ----------------
__global__ __launch_bounds__(256) void k_softmax(float* __restrict__ sc){
  __shared__ float red[256];
  int b = blockIdx.x, t = threadIdx.x;
  float v[16]; float m = -INFINITY;
  #pragma unroll
  for (int i = 0; i < 16; ++i){ v[i] = sc[b*4096 + i*256 + t]; m = fmaxf(m, v[i]); }
  red[t] = m; __syncthreads();
  for (int s = 128; s > 0; s >>= 1){ if (t < s) red[t] = fmaxf(red[t], red[t+s]); __syncthreads(); }
  m = red[0]; __syncthreads();
  float sum = 0.f;
  #pragma unroll
  for (int i = 0; i < 16; ++i){ v[i] = expf(v[i] - m); sum += v[i]; }
  red[t] = sum; __syncthreads();
  for (int s = 128; s > 0; s >>= 1){ if (t < s) red[t] += red[t+s]; __syncthreads(); }
  float inv = 1.f / red[0];
  #pragma unroll
  for (int i = 0; i < 16; ++i) sc[b*4096 + i*256 + t] = v[i] * inv;
}

// ---------------- context partials ----------------
#define CCH 64
__global__ __launch_bounds__(256) void k_ctx(
    const float* __restrict__ attn, const float* __restrict__ doc,
    float* __restrict__ ctxp){
  __shared__ float sa[CCH];
  int b = blockIdx.y, ch = blockIdx.x, t = threadIdx.x;
  int l0 = ch * CCH;
  if (t < CCH) sa[t] = attn[b*4096 + l0 + t];
  __syncthreads();
  const float* dp = doc + (((long)b*4096 + l0) << 9) + t*2;
  float ax = 0.f, ay = 0.f;
  #pragma unroll 4
  for (int l = 0; l < CCH; ++l){
    f32x2 d = *(const f32x2*)dp;
    float a = sa[l];
    ax += a * d[0]; ay += a * d[1];
    dp += 512;
  }
  int o = (b*64 + ch)*512 + t*2;
  ctxp[o] = ax; ctxp[o+1] = ay;
}

__global__ __launch_bounds__(256) void k_ctx_reduce(
    const float* __restrict__ ctxp, float* __restrict__ cc,
    unsigned short* __restrict__ ccb){
  int idx = blockIdx.x*256 + threadIdx.x;  // 16384
  int b = idx >> 9, hh = idx & 511;
  float s = 0.f;
  #pragma unroll 8
  for (int ch = 0; ch < 64; ++ch) s += ctxp[(b*64 + ch)*512 + hh];
  cc[b*1024 + 512 + hh] = s;
  ccb[b*1024 + 512 + hh] = bf16_rne(s);
}

// ---------------- output = cc @ Wout^T + bout, bf16 MFMA ----------------
__global__ __launch_bounds__(256) void k_out(
    const unsigned short* __restrict__ ccb, const float* __restrict__ Wout,
    const float* __restrict__ bout, float* __restrict__ out){
  __shared__ short Ccb[32][128][8];      // 64 KB
  __shared__ float s_out[32][65];        // 8.3 KB
  int t = threadIdx.x, wave = t >> 6, lane = t & 63;
  int v0 = blockIdx.x * 64;
  #pragma unroll
  for (int i = 0; i < 16; ++i){
    int c16 = i*256 + t;               // 16B-chunk index over 4096
    int bb = c16 >> 7, ch = c16 & 127;
    int chsw = (ch & ~7) | ((ch & 7) ^ (bb & 7));
    *(short8*)&Ccb[bb][chsw][0] = *(const short8*)(ccb + c16*8);
  }
  __syncthreads();

  int lrow = lane & 15, lk = lane >> 4;
  int vrow = v0 + wave*16 + lrow;
  const float* wptr = Wout + (long)vrow*1024 + lk*8;
  f32x4 acc[2];
  acc[0] = (f32x4){0.f,0.f,0.f,0.f};
  acc[1] = (f32x4){0.f,0.f,0.f,0.f};
  int sw = lrow & 7;
  f32x4 w0 = *(const f32x4*)(wptr);
  f32x4 w1 = *(const f32x4*)(wptr + 4);
  #pragma unroll 4
  for (int ks = 0; ks < 32; ++ks){
    f32x4 nw0, nw1;
    if (ks < 31){
      nw0 = *(const f32x4*)(wptr + (ks+1)*32);
      nw1 = *(const f32x4*)(wptr + (ks+1)*32 + 4);
    }
    short8 bfrag = cvt8(w0, w1);
    int ch = ks*4 + lk;
    int chsw = (ch & ~7) | ((ch & 7) ^ sw);
    short8 a0 = *(const short8*)&Ccb[lrow][chsw][0];
    short8 a1 = *(const short8*)&Ccb[16 + lrow][chsw][0];
    acc[0] = __builtin_amdgcn_mfma_f32_16x16x32_bf16(bfrag, a0, acc[0], 0, 0, 0);
    acc[1] = __builtin_amdgcn_mfma_f32_16x16x32_bf16(bfrag, a1, acc[1], 0, 0, 0);
    w0 = nw0; w1 = nw1;
  }
  #pragma unroll
  for (int mt = 0; mt < 2; ++mt)
    #pragma unroll
    for (int r = 0; r < 4; ++r)
      s_out[mt*16 + lrow][wave*16 + lk*4 + r] = acc[mt][r];
  __syncthreads();
  int vcol = t & 63, bq = t >> 6;
  float bo = bout[v0 + vcol];
  #pragma unroll
  for (int bb = 0; bb < 8; ++bb){
    int brow = bb*4 + bq;
    out[(long)brow*V_ + v0 + vcol] = s_out[brow][vcol] + bo;
  }
}

extern "C" void kernel_launch(void* const* d_in, const int* in_sizes, int n_in,
                              void* d_out, int out_size, void* d_ws, size_t ws_size,
                              hipStream_t stream){
  const float* x    = (const float*)d_in[0];
  const float* h0   = (const float*)d_in[1];
  const float* c0   = (const float*)d_in[2];
  const float* doc  = (const float*)d_in[3];
  const int*   mask = (const int*)d_in[4];
  const float* Wih  = (const float*)d_in[5];
  const float* Whh  = (const float*)d_in[6];
  const float* bih  = (const float*)d_in[7];
  const float* bhh  = (const float*)d_in[8];
  const float* W1   = (const float*)d_in[9];
  const float* b1   = (const float*)d_in[10];
  const float* W2   = (const float*)d_in[11];
  const float* b2   = (const float*)d_in[12];
  const float* u1   = (const float*)d_in[13];
  const float* Wo   = (const float*)d_in[14];
  const float* bo   = (const float*)d_in[15];
  float* out  = (float*)d_out;
  float* outh = out + B_*V_;
  float* outc = outh + B_*H_;

  float* ws    = (float*)d_ws;
  float* gates = ws;                  // 65536 f32
  float* q     = gates + 65536;       // 16384
  float* cc    = q + 16384;           // 32768
  float* attn  = cc + 32768;          // 131072
  float* ctxp  = attn + 131072;       // 1048576
  unsigned short* w2hi = (unsigned short*)(ctxp + 1048576); // 262144 u16
  unsigned short* ccb  = w2hi + 262144;                      // 32768 u16

  hipLaunchKernelGGL(k_convert_w2, dim3(256), dim3(256), 0, stream, W2, w2hi);
  hipLaunchKernelGGL(k_gates, dim3(8, 32), dim3(256), 0, stream, x, h0, Wih, Whh, bih, bhh, gates);
  hipLaunchKernelGGL(k_lstm, dim3(64), dim3(256), 0, stream, gates, c0, outh, outc, cc, ccb);
  hipLaunchKernelGGL(k_q, dim3(2, 32), dim3(256), 0, stream, cc, W1, b1, q);
  hipLaunchKernelGGL(k_scores, dim3(1024), dim3(512), 0, stream, doc, w2hi, q, b2, u1, mask, attn);
  hipLaunchKernelGGL(k_softmax, dim3(32), dim3(256), 0, stream, attn);
  hipLaunchKernelGGL(k_ctx, dim3(64, 32), dim3(256), 0, stream, attn, doc, ctxp);
  hipLaunchKernelGGL(k_ctx_reduce, dim3(64), dim3(256), 0, stream, ctxp, cc, ccb);
  hipLaunchKernelGGL(k_out, dim3(500), dim3(256), 0, stream, ccb, Wo, bo, out);
}